// Round 1
// baseline (5583.406 us; speedup 1.0000x reference)
//
#include <hip/hip_runtime.h>
#include <math.h>

#define NB 32
#define NC 72
#define NT 1000
#define NF 64
#define NH 512
#define NCLS 3

// ---- workspace layout (float indices) ----
#define OFF_WT      0            // Wt[k][j] = W[j][k], 512*512
#define OFF_WINT    262144       // w_inT[f][h] = w_in[h][f], 64*512
#define OFF_FEATS   294912       // feats[b][t][f], 32*1000*64
#define OFF_POOLED  2342912      // pooled[b][h], 32*512
#define OFF_HX      2359296      // hx[2][b][h], 2*32*512
#define OFF_FLAGS   2392064      // int flags[32][64] (256B row per batch)
#define WS_FLOATS   2394112

// padded LDS index for h (breaks 4-way bank aliasing of the p*128 strides)
#define HIDX(k) ((k) + (((k) >> 7) << 2))

// ---------------- prep: transposes + flag reset (runs every launch/replay) ----
__global__ void prep_kernel(const float* __restrict__ Wm,
                            const float* __restrict__ w_in,
                            float* __restrict__ ws_f,
                            int* __restrict__ flags) {
  int i = blockIdx.x * 256 + threadIdx.x;
  if (i < NH * NH) {
    int j = i / NH, k = i % NH;                 // coalesced read of W[j][k]
    ws_f[OFF_WT + k * NH + j] = Wm[i];
  }
  if (i < NH * NF) {
    int h = i / NF, f = i % NF;                 // coalesced read of w_in[h][f]
    ws_f[OFF_WINT + f * NH + h] = w_in[i];
  }
  if (i < NB * 64) flags[i] = 0;
}

// ---------------- fused front-end: conv5 + BN1 + ELU + spatial + BN2 + ELU ----
__global__ __launch_bounds__(256) void frontend_kernel(
    const float* __restrict__ x, const float* __restrict__ w_temp,
    const float* __restrict__ g1, const float* __restrict__ be1,
    const float* __restrict__ m1, const float* __restrict__ v1,
    const float* __restrict__ wsp,
    const float* __restrict__ g2, const float* __restrict__ be2,
    const float* __restrict__ m2, const float* __restrict__ v2,
    float* __restrict__ feats) {
  const int b = blockIdx.y;
  const int t0 = blockIdx.x * 64;

  __shared__ float xs[NC][68];
  for (int idx = threadIdx.x; idx < NC * 68; idx += 256) {
    int c = idx / 68, tt = idx % 68;
    int tg = t0 - 2 + tt;
    xs[c][tt] = (tg >= 0 && tg < NT) ? x[(b * NC + c) * NT + tg] : 0.0f;
  }
  __syncthreads();

  const int f = threadIdx.x & 63;   // lane == f -> xs reads broadcast, feats writes coalesced
  const int tq = threadIdx.x >> 6;  // wave id

  const float w0 = w_temp[f * 5 + 0], w1 = w_temp[f * 5 + 1], w2 = w_temp[f * 5 + 2],
              w3 = w_temp[f * 5 + 3], w4 = w_temp[f * 5 + 4];
  const float sc1 = g1[f] * rsqrtf(v1[f] + 1e-5f);
  const float sh1 = be1[f] - m1[f] * sc1;
  const float sc2 = g2[f] * rsqrtf(v2[f] + 1e-5f);
  const float sh2 = be2[f] - m2[f] * sc2;

  for (int i = 0; i < 16; ++i) {
    const int tl = tq + 4 * i;
    const int t = t0 + tl;
    if (t >= NT) break;
    float acc = 0.0f;
    for (int c = 0; c < NC; ++c) {
      const float* xr = &xs[c][tl];
      float conv = xr[0] * w0 + xr[1] * w1 + xr[2] * w2 + xr[3] * w3 + xr[4] * w4;
      float bn = conv * sc1 + sh1;
      float e = bn > 0.0f ? bn : expm1f(bn);
      acc += e * wsp[f * NC + c];
    }
    float bn2 = acc * sc2 + sh2;
    float e2 = bn2 > 0.0f ? bn2 : expm1f(bn2);
    feats[(b * NT + t) * NF + f] = e2;
  }
}

// ---------------- ESN scan: 32 batches x 8 col-groups, W in VGPRs ----
__global__ __launch_bounds__(256, 1) void esn_scan(
    const float* __restrict__ ws_f, const float* __restrict__ b_in,
    float* __restrict__ hx, int* __restrict__ flags,
    float* __restrict__ pooled) {
  const int b = blockIdx.x & 31;    // members of batch b = blocks {b, b+32, ...}: same XCD mod-8
  const int m = blockIdx.x >> 5;    // col-group 0..7
  const int tid = threadIdx.x;
  const int jl = tid >> 2;          // 0..63  local output column
  const int p = tid & 3;            // k-quarter / f-quarter
  const int j = m * 64 + jl;        // global output column

  const float* __restrict__ Wt = ws_f + OFF_WT;
  const float* __restrict__ w_inT = ws_f + OFF_WINT;
  const float* __restrict__ feats = ws_f + OFF_FEATS;

  __shared__ __align__(16) float h_s[NH + 16];
  __shared__ __align__(16) float f_s[NF];

  // W slice: thread owns column j, k-range [p*128, p*128+128)
  float w[128];
#pragma unroll
  for (int i = 0; i < 128; ++i) w[i] = Wt[(p * 128 + i) * NH + j];
  // w_in slice: f-range [p*16, p*16+16)
  float wu[16];
#pragma unroll
  for (int i = 0; i < 16; ++i) wu[i] = w_inT[(p * 16 + i) * NH + j];
  const float bias = (p == 0) ? b_in[j] : 0.0f;

  for (int i = tid; i < NH; i += 256) h_s[HIDX(i)] = 0.0f;
  if (tid < NF) f_s[tid] = feats[(b * NT) * NF + tid];
  __syncthreads();

  float pool = 0.0f;
  int* gflags = flags + b * 64;
  int budget = 20000000;  // safety: degrade to wrong-answer instead of hang

#pragma unroll 1
  for (int t = 0; t < NT; ++t) {
    float acc = bias;
#pragma unroll
    for (int i = 0; i < 16; i += 4) {   // u-projection (f-quarter)
      float4 fv = *(const float4*)&f_s[p * 16 + i];
      acc += fv.x * wu[i] + fv.y * wu[i + 1] + fv.z * wu[i + 2] + fv.w * wu[i + 3];
    }
#pragma unroll
    for (int i = 0; i < 128; i += 4) {  // W matvec (k-quarter)
      float4 hv = *(const float4*)&h_s[HIDX(p * 128 + i)];
      acc += hv.x * w[i] + hv.y * w[i + 1] + hv.z * w[i + 2] + hv.w * w[i + 3];
    }
    acc += __shfl_xor(acc, 1);          // combine the 4 quarters of column j
    acc += __shfl_xor(acc, 2);
    const float hprev = h_s[HIDX(j)];
    const float hn = 0.9f * hprev + 0.1f * tanhf(acc);
    if (p == 0) pool += hn;
    if (t == NT - 1) break;

    // ---- exchange h_{t+1} among the batch's 8 WGs (double-buffered) ----
    float* hxb = hx + ((t + 1) & 1) * (NB * NH);
    if (p == 0)
      __hip_atomic_store(&hxb[b * NH + j], hn, __ATOMIC_RELAXED, __HIP_MEMORY_SCOPE_AGENT);
    __syncthreads();
    if (tid == 0)
      __hip_atomic_store(&gflags[m], t + 1, __ATOMIC_RELEASE, __HIP_MEMORY_SCOPE_AGENT);

    // prefetch next feats row while polling
    float fnext = 0.0f;
    if (tid < NF) fnext = feats[(b * NT + t + 1) * NF + tid];

    if (tid < 8) {
      while (__hip_atomic_load(&gflags[tid], __ATOMIC_ACQUIRE, __HIP_MEMORY_SCOPE_AGENT) <= t) {
        if (--budget < 0) break;
        __builtin_amdgcn_s_sleep(1);
      }
    }
    __syncthreads();

    const int k0 = tid * 2;
    float a0 = __hip_atomic_load(&hxb[b * NH + k0], __ATOMIC_RELAXED, __HIP_MEMORY_SCOPE_AGENT);
    float a1 = __hip_atomic_load(&hxb[b * NH + k0 + 1], __ATOMIC_RELAXED, __HIP_MEMORY_SCOPE_AGENT);
    h_s[HIDX(k0)] = a0;
    h_s[HIDX(k0 + 1)] = a1;
    if (tid < NF) f_s[tid] = fnext;
    __syncthreads();
  }

  if (p == 0) pooled[b * NH + j] = pool * (1.0f / NT);
}

// ---------------- classifier head ----
__global__ void classifier_kernel(const float* __restrict__ pooled,
                                  const float* __restrict__ w_cls,
                                  const float* __restrict__ b_cls,
                                  float* __restrict__ out) {
  const int b = blockIdx.x;
  const int lane = threadIdx.x;  // 64
  float a0 = 0.0f, a1 = 0.0f, a2 = 0.0f;
  for (int jj = lane; jj < NH; jj += 64) {
    float pv = pooled[b * NH + jj];
    a0 += pv * w_cls[0 * NH + jj];
    a1 += pv * w_cls[1 * NH + jj];
    a2 += pv * w_cls[2 * NH + jj];
  }
  for (int off = 32; off; off >>= 1) {
    a0 += __shfl_down(a0, off);
    a1 += __shfl_down(a1, off);
    a2 += __shfl_down(a2, off);
  }
  if (lane == 0) {
    out[b * NCLS + 0] = a0 + b_cls[0];
    out[b * NCLS + 1] = a1 + b_cls[1];
    out[b * NCLS + 2] = a2 + b_cls[2];
  }
}

extern "C" void kernel_launch(void* const* d_in, const int* in_sizes, int n_in,
                              void* d_out, int out_size, void* d_ws, size_t ws_size,
                              hipStream_t stream) {
  (void)in_sizes; (void)n_in; (void)out_size;
  if (ws_size < (size_t)WS_FLOATS * 4) return;  // fail cleanly if ws too small

  const float* x      = (const float*)d_in[0];
  const float* w_temp = (const float*)d_in[1];
  const float* g1  = (const float*)d_in[2];
  const float* be1 = (const float*)d_in[3];
  const float* m1  = (const float*)d_in[4];
  const float* v1  = (const float*)d_in[5];
  const float* wsp = (const float*)d_in[6];
  const float* g2  = (const float*)d_in[7];
  const float* be2 = (const float*)d_in[8];
  const float* m2  = (const float*)d_in[9];
  const float* v2  = (const float*)d_in[10];
  const float* w_in  = (const float*)d_in[11];
  const float* b_in  = (const float*)d_in[12];
  const float* Wm    = (const float*)d_in[13];
  const float* w_cls = (const float*)d_in[14];
  const float* b_cls = (const float*)d_in[15];

  float* ws_f  = (float*)d_ws;
  float* feats = ws_f + OFF_FEATS;
  float* pooledp = ws_f + OFF_POOLED;
  float* hx    = ws_f + OFF_HX;
  int* flags   = (int*)(ws_f + OFF_FLAGS);

  prep_kernel<<<1024, 256, 0, stream>>>(Wm, w_in, ws_f, flags);

  dim3 gfe(16, NB);
  frontend_kernel<<<gfe, 256, 0, stream>>>(x, w_temp, g1, be1, m1, v1, wsp,
                                           g2, be2, m2, v2, feats);

  esn_scan<<<256, 256, 0, stream>>>(ws_f, b_in, hx, flags, pooledp);

  classifier_kernel<<<NB, 64, 0, stream>>>(pooledp, w_cls, b_cls, (float*)d_out);
}

// Round 2
// 1810.920 us; speedup vs baseline: 3.0832x; 3.0832x over previous
//
#include <hip/hip_runtime.h>
#include <math.h>

#define NB 32
#define NC 72
#define NT 1000
#define NF 64
#define NH 512
#define NCLS 3

// ---- workspace layout (float indices) ----
#define OFF_WT      0            // Wt[k][j] = W[j][k], 512*512
#define OFF_WINT    262144       // w_inT[f][h] = w_in[h][f], 64*512
#define OFF_FEATS   294912       // feats[b][t][f], 32*1000*64
#define OFF_POOLED  2342912      // pooled[b][h], 32*512
#define OFF_HX      2359296      // u64 hx[2][b][h] = {epoch:32|float:32}, 2*32*512 (8B aligned)
#define WS_FLOATS   2424832

// padded LDS index for h (keeps the four p-groups' float4 reads on disjoint banks)
#define HIDX(k) ((k) + (((k) >> 7) << 2))

// ---------------- prep: transposes + epoch reset (runs every launch/replay) ----
__global__ void prep_kernel(const float* __restrict__ Wm,
                            const float* __restrict__ w_in,
                            float* __restrict__ ws_f) {
  int i = blockIdx.x * 256 + threadIdx.x;
  if (i < NH * NH) {
    int j = i / NH, k = i % NH;                 // coalesced read of W[j][k]
    ws_f[OFF_WT + k * NH + j] = Wm[i];
  }
  if (i < NH * NF) {
    int h = i / NF, f = i % NF;                 // coalesced read of w_in[h][f]
    ws_f[OFF_WINT + f * NH + h] = w_in[i];
  }
  if (i < 2 * NB * NH) {                        // zero the {epoch|value} exchange buffers
    ((unsigned long long*)(ws_f + OFF_HX))[i] = 0ull;
  }
}

// ---------------- fused front-end: conv5 + BN1 + ELU + spatial + BN2 + ELU ----
__global__ __launch_bounds__(256) void frontend_kernel(
    const float* __restrict__ x, const float* __restrict__ w_temp,
    const float* __restrict__ g1, const float* __restrict__ be1,
    const float* __restrict__ m1, const float* __restrict__ v1,
    const float* __restrict__ wsp,
    const float* __restrict__ g2, const float* __restrict__ be2,
    const float* __restrict__ m2, const float* __restrict__ v2,
    float* __restrict__ feats) {
  const int b = blockIdx.y;
  const int t0 = blockIdx.x * 64;

  __shared__ float xs[NC][68];
  for (int idx = threadIdx.x; idx < NC * 68; idx += 256) {
    int c = idx / 68, tt = idx % 68;
    int tg = t0 - 2 + tt;
    xs[c][tt] = (tg >= 0 && tg < NT) ? x[(b * NC + c) * NT + tg] : 0.0f;
  }
  __syncthreads();

  const int f = threadIdx.x & 63;   // lane == f -> xs reads broadcast, feats writes coalesced
  const int tq = threadIdx.x >> 6;  // wave id

  const float w0 = w_temp[f * 5 + 0], w1 = w_temp[f * 5 + 1], w2 = w_temp[f * 5 + 2],
              w3 = w_temp[f * 5 + 3], w4 = w_temp[f * 5 + 4];
  const float sc1 = g1[f] * rsqrtf(v1[f] + 1e-5f);
  const float sh1 = be1[f] - m1[f] * sc1;
  const float sc2 = g2[f] * rsqrtf(v2[f] + 1e-5f);
  const float sh2 = be2[f] - m2[f] * sc2;

  for (int i = 0; i < 16; ++i) {
    const int tl = tq + 4 * i;
    const int t = t0 + tl;
    if (t >= NT) break;
    float acc = 0.0f;
    for (int c = 0; c < NC; ++c) {
      const float* xr = &xs[c][tl];
      float conv = xr[0] * w0 + xr[1] * w1 + xr[2] * w2 + xr[3] * w3 + xr[4] * w4;
      float bn = conv * sc1 + sh1;
      float e = bn > 0.0f ? bn : __expf(bn) - 1.0f;   // fast ELU (|err| ~1e-7, thr 2.9e-3)
      acc += e * wsp[f * NC + c];
    }
    float bn2 = acc * sc2 + sh2;
    float e2 = bn2 > 0.0f ? bn2 : __expf(bn2) - 1.0f;
    feats[(b * NT + t) * NF + f] = e2;
  }
}

// ---------------- ESN scan: 32 batches x 4 col-groups, W pinned in VGPRs ----
// grid 128: bid = m*32 + b  (all members of batch b share bid%8 -> same XCD heuristic)
__global__ __launch_bounds__(512, 2) void esn_scan(
    const float* __restrict__ ws_f, const float* __restrict__ b_in,
    unsigned long long* __restrict__ hx, float* __restrict__ pooled) {
  const int b = blockIdx.x & 31;
  const int m = blockIdx.x >> 5;    // col-group 0..3 (128 cols each)
  const int tid = threadIdx.x;      // 0..511
  const int jl = tid >> 2;          // 0..127 local output column
  const int p = tid & 3;            // k-quarter / f-quarter
  const int j = m * 128 + jl;       // global output column

  const float* __restrict__ Wt = ws_f + OFF_WT;
  const float* __restrict__ w_inT = ws_f + OFF_WINT;
  const float* __restrict__ feats = ws_f + OFF_FEATS;

  __shared__ __align__(16) float h_s[NH + 16];
  __shared__ __align__(16) float f_s[NF];

  // W slice: thread owns column j, k-range [p*128, p*128+128)
  float w[128];
#pragma unroll
  for (int i = 0; i < 128; ++i) w[i] = Wt[(p * 128 + i) * NH + j];
#pragma unroll
  for (int i = 0; i < 128; ++i) asm volatile("" : "+v"(w[i]));  // pin: no remat/sink
  // w_in slice: f-range [p*16, p*16+16)
  float wu[16];
#pragma unroll
  for (int i = 0; i < 16; ++i) wu[i] = w_inT[(p * 16 + i) * NH + j];
#pragma unroll
  for (int i = 0; i < 16; ++i) asm volatile("" : "+v"(wu[i]));
  const float bias = (p == 0) ? b_in[j] : 0.0f;

  for (int i = tid; i < NH; i += 512) h_s[HIDX(i)] = 0.0f;
  if (tid < NF) f_s[tid] = feats[(b * NT) * NF + tid];
  __syncthreads();

  float pool = 0.0f;
  int budget = 2000000;  // safety: degrade to wrong-answer instead of hang

#pragma unroll 1
  for (int t = 0; t < NT; ++t) {
    float acc = bias;
#pragma unroll
    for (int i = 0; i < 16; i += 4) {   // u-projection (f-quarter)
      float4 fv = *(const float4*)&f_s[p * 16 + i];
      acc += fv.x * wu[i] + fv.y * wu[i + 1] + fv.z * wu[i + 2] + fv.w * wu[i + 3];
    }
#pragma unroll
    for (int i = 0; i < 128; i += 4) {  // W matvec (k-quarter)
      float4 hv = *(const float4*)&h_s[HIDX(p * 128 + i)];
      acc += hv.x * w[i] + hv.y * w[i + 1] + hv.z * w[i + 2] + hv.w * w[i + 3];
    }
    acc += __shfl_xor(acc, 1);          // combine the 4 quarters of column j
    acc += __shfl_xor(acc, 2);
    const float hn = 0.9f * h_s[HIDX(j)] + 0.1f * tanhf(acc);
    if (p == 0) pool += hn;
    if (t == NT - 1) break;

    // publish own column IMMEDIATELY: one 8B atomic carries {epoch, value}
    unsigned long long* hxb = hx + ((t + 1) & 1) * (NB * NH) + b * NH;
    if (p == 0) {
      unsigned long long pk =
          ((unsigned long long)(unsigned)(t + 1) << 32) | (unsigned)__float_as_uint(hn);
      __hip_atomic_store(&hxb[j], pk, __ATOMIC_RELAXED, __HIP_MEMORY_SCOPE_AGENT);
    }

    __syncthreads();                    // all step-t LDS reads complete
    if (p == 0) h_s[HIDX(j)] = hn;      // own columns: no round trip

    // prefetch next feats row; its latency hides under the poll
    float fnext = 0.0f;
    if (tid < NF) fnext = feats[(b * NT + t + 1) * NF + tid];

    const int k = tid;                  // 512 threads cover the 512 h-values
    if ((k >> 7) != m) {                // poll the other 3 groups' values
      unsigned long long q;
      for (;;) {
        q = __hip_atomic_load(&hxb[k], __ATOMIC_RELAXED, __HIP_MEMORY_SCOPE_AGENT);
        if ((unsigned)(q >> 32) == (unsigned)(t + 1)) break;
        if (--budget < 0) break;
        __builtin_amdgcn_s_sleep(1);
      }
      h_s[HIDX(k)] = __uint_as_float((unsigned)q);
    }
    if (tid < NF) f_s[tid] = fnext;
    __syncthreads();
  }

  if (p == 0) pooled[b * NH + j] = pool * (1.0f / NT);
}

// ---------------- classifier head ----
__global__ void classifier_kernel(const float* __restrict__ pooled,
                                  const float* __restrict__ w_cls,
                                  const float* __restrict__ b_cls,
                                  float* __restrict__ out) {
  const int b = blockIdx.x;
  const int lane = threadIdx.x;  // 64
  float a0 = 0.0f, a1 = 0.0f, a2 = 0.0f;
  for (int jj = lane; jj < NH; jj += 64) {
    float pv = pooled[b * NH + jj];
    a0 += pv * w_cls[0 * NH + jj];
    a1 += pv * w_cls[1 * NH + jj];
    a2 += pv * w_cls[2 * NH + jj];
  }
  for (int off = 32; off; off >>= 1) {
    a0 += __shfl_down(a0, off);
    a1 += __shfl_down(a1, off);
    a2 += __shfl_down(a2, off);
  }
  if (lane == 0) {
    out[b * NCLS + 0] = a0 + b_cls[0];
    out[b * NCLS + 1] = a1 + b_cls[1];
    out[b * NCLS + 2] = a2 + b_cls[2];
  }
}

extern "C" void kernel_launch(void* const* d_in, const int* in_sizes, int n_in,
                              void* d_out, int out_size, void* d_ws, size_t ws_size,
                              hipStream_t stream) {
  (void)in_sizes; (void)n_in; (void)out_size;
  if (ws_size < (size_t)WS_FLOATS * 4) return;  // fail cleanly if ws too small

  const float* x      = (const float*)d_in[0];
  const float* w_temp = (const float*)d_in[1];
  const float* g1  = (const float*)d_in[2];
  const float* be1 = (const float*)d_in[3];
  const float* m1  = (const float*)d_in[4];
  const float* v1  = (const float*)d_in[5];
  const float* wsp = (const float*)d_in[6];
  const float* g2  = (const float*)d_in[7];
  const float* be2 = (const float*)d_in[8];
  const float* m2  = (const float*)d_in[9];
  const float* v2  = (const float*)d_in[10];
  const float* w_in  = (const float*)d_in[11];
  const float* b_in  = (const float*)d_in[12];
  const float* Wm    = (const float*)d_in[13];
  const float* w_cls = (const float*)d_in[14];
  const float* b_cls = (const float*)d_in[15];

  float* ws_f  = (float*)d_ws;
  float* feats = ws_f + OFF_FEATS;
  float* pooledp = ws_f + OFF_POOLED;
  unsigned long long* hx = (unsigned long long*)(ws_f + OFF_HX);

  prep_kernel<<<1024, 256, 0, stream>>>(Wm, w_in, ws_f);

  dim3 gfe(16, NB);
  frontend_kernel<<<gfe, 256, 0, stream>>>(x, w_temp, g1, be1, m1, v1, wsp,
                                           g2, be2, m2, v2, feats);

  esn_scan<<<128, 512, 0, stream>>>(ws_f, b_in, hx, pooledp);

  classifier_kernel<<<NB, 64, 0, stream>>>(pooledp, w_cls, b_cls, (float*)d_out);
}